// Round 12
// baseline (185.583 us; speedup 1.0000x reference)
//
#include <hip/hip_runtime.h>
#include <stdint.h>

// ---------------------------------------------------------------------------
// NonLocalBlock2D  B=16, C=512, I=256, N=3136.  (R11 + fp8 P/G2)
//   xb  [b][3136][512] = x^T bf16
//   G1 (MODE1): m-tiles 0-3 -> P8[b][512][3136] fp8 e4m3 (g,ph)
//               m-tiles 4-5 -> thT bf16 (transposed store)
//   g2_fp8:     Mf2 partials = ph8 .NT g8, split-K 7x448, fp8 MFMA
//   cvt: MT2 = (1/N) sum partials (bf16)
//   GU (MODE6): U = Ww .NT MT2
//   G4 (MODE4): out = U .NT thT + x + W_b  (f32 LDS-roundtrip epilogue)
// Workspace:
//   xb  @ 0          : 51,380,224 (dead after G1; Mf2/MT2/U alias)
//   P8  @ 51,380,224 : 25,690,112
//   thT @ 77,070,336 : 26,214,400 (+64KB tail slop)
//   W3  @ 103,415,808:    786,432
//   Wwb @ 104,202,240:    262,144
//   bias3 @ 104,464,384:    3,072   total ~104.5 MB
// ---------------------------------------------------------------------------

typedef unsigned short ushort_t;
typedef __attribute__((ext_vector_type(8))) short short8;
typedef __attribute__((ext_vector_type(4))) float f32x4;
typedef __attribute__((ext_vector_type(8))) unsigned short us8;

#define NSP  3136

#define AS1(p) ((const __attribute__((address_space(1))) void*)(p))
#define AS3(p) ((__attribute__((address_space(3))) void*)(p))

__device__ inline ushort_t f2b(float f) {
  union { float f; uint32_t u; } c; c.f = f;
  uint32_t u = c.u;
  uint32_t r = (u + 0x7fffu + ((u >> 16) & 1u)) >> 16;
  return (ushort_t)r;
}

// f32 -> fp8 e4m3fn, RNE, FTZ below 2^-6 (error irrelevant at our scale)
__device__ inline unsigned char f2e4m3(float f) {
  union { float f; uint32_t u; } c; c.f = f;
  uint32_t s = (c.u >> 24) & 0x80;
  float af = fabsf(f);
  if (!(af >= 0x1p-6f)) return (unsigned char)s;
  if (af > 448.f) af = 448.f;
  c.f = af;
  uint32_t u = c.u;
  uint32_t md = (u >> 20) & 7;
  uint32_t rem = u & 0xFFFFF;
  uint32_t ee = ((u >> 23) & 0xFF) - 120;   // e + 7
  if (rem > 0x80000u || (rem == 0x80000u && (md & 1))) { md++; if (md == 8) { md = 0; ee++; } }
  if (ee > 15 || (ee == 15 && md > 6)) { ee = 15; md = 6; }
  return (unsigned char)(s | (ee << 3) | md);
}

// MODE 1: G1 : A=W3[768][512], B=xb_b, K=512.  C-> P8 fp8 (m0<512) / thT bf16
// MODE 6: GU : U = Ww .NT MT2  (K=256) bf16
// MODE 4: G4 : out = U .NT thT + x + W_b (K=256) f32
template<int MODE>
__global__ __launch_bounds__(256, 2) void gemm64(
    const ushort_t* __restrict__ Abase,
    const ushort_t* __restrict__ Bbase,
    void* __restrict__ Cbase, void* __restrict__ C2,
    const float* __restrict__ bias,
    const float* __restrict__ xres)
{
  constexpr int TB = 256;
  constexpr int CH = TB / 8;

  const int nwg = gridDim.x * gridDim.y * gridDim.z;
  int flat = blockIdx.x + gridDim.x * (blockIdx.y + gridDim.y * blockIdx.z);
  const int q = nwg >> 3;
  int swz = (flat & 7) * q + (flat >> 3);
  const int bx = swz % gridDim.x; int tmp = swz / gridDim.x;
  const int by = tmp % gridDim.y;
  const int bz = tmp / gridDim.y;

  int b = bz, kend, lda, ldb;
  const ushort_t *A, *B;
  if constexpr (MODE == 1) {
    A = Abase;                                   // W3
    B = Bbase + (size_t)b * 1605632;             // xb_b (3136x512)
    lda = 512; ldb = 512; kend = 512;
  } else if constexpr (MODE == 6) {
    A = Abase; lda = 256;                        // Wwb [512][256]
    B = Bbase + (size_t)b * 65536; ldb = 256;    // MT2_b
    kend = 256;
  } else {
    A = Abase + (size_t)b * 131072; lda = 256;   // U_b [512][256]
    B = Bbase + (size_t)b * 819200; ldb = 256;   // thT_b ([3200][256] alloc)
    kend = 256;
  }

  const int m0 = bx * 128;
  const int n0 = by * 128;
  const int tid = threadIdx.x;
  const int lane = tid & 63;
  const int wid = tid >> 6;
  const int wm = wid >> 1, wn = wid & 1;
  const int fr = lane & 15;
  const int fk = lane >> 4;

  __shared__ __align__(16) ushort_t SMu[32768];   // 64 KiB: As | Bs, reused by epilogues
  ushort_t (*As)[8192] = (ushort_t(*)[8192])(SMu);
  ushort_t (*Bs)[8192] = (ushort_t(*)[8192])(SMu + 16384);

  f32x4 acc[4][4];
#pragma unroll
  for (int i = 0; i < 4; ++i)
#pragma unroll
    for (int j = 0; j < 4; ++j) acc[i][j] = f32x4{0.f, 0.f, 0.f, 0.f};

  const int srow = tid >> 3;
  const int lsl = (tid & 7) ^ (srow & 7);
  const ushort_t* pa = A + (size_t)(m0 + srow) * lda + lsl * 8;
  const ushort_t* pb = B + (size_t)(n0 + srow) * ldb + lsl * 8;

#define STAGE(bufi) do {                                                              \
    __builtin_amdgcn_global_load_lds(AS1(pa),                    AS3(&As[bufi][tid * 8]), 16, 0, 0); \
    __builtin_amdgcn_global_load_lds(AS1(pa + (size_t)CH * lda), AS3(&As[bufi][TB * 8 + tid * 8]), 16, 0, 0); \
    __builtin_amdgcn_global_load_lds(AS1(pa + (size_t)2 * CH * lda), AS3(&As[bufi][2 * TB * 8 + tid * 8]), 16, 0, 0); \
    __builtin_amdgcn_global_load_lds(AS1(pa + (size_t)3 * CH * lda), AS3(&As[bufi][3 * TB * 8 + tid * 8]), 16, 0, 0); \
    __builtin_amdgcn_global_load_lds(AS1(pb),                    AS3(&Bs[bufi][tid * 8]), 16, 0, 0); \
    __builtin_amdgcn_global_load_lds(AS1(pb + (size_t)CH * ldb), AS3(&Bs[bufi][TB * 8 + tid * 8]), 16, 0, 0); \
    __builtin_amdgcn_global_load_lds(AS1(pb + (size_t)2 * CH * ldb), AS3(&Bs[bufi][2 * TB * 8 + tid * 8]), 16, 0, 0); \
    __builtin_amdgcn_global_load_lds(AS1(pb + (size_t)3 * CH * ldb), AS3(&Bs[bufi][3 * TB * 8 + tid * 8]), 16, 0, 0); \
    pa += 64; pb += 64;                                                               \
  } while (0)

  const int sw = fr & 7;
  const int s0 = ((0 | fk) ^ sw) * 8;
  const int s1 = ((4 | fk) ^ sw) * 8;
  const int arow = (wm * 64 + fr) * 64;
  const int brow = (wn * 64 + fr) * 64;

  asm volatile("s_waitcnt vmcnt(0)" ::: "memory");
  STAGE(0);

  const int nkt = kend >> 6;
  for (int t = 0; t < nkt; ++t) {
    const int cur = t & 1;
    if (t + 1 < nkt) {
      STAGE(cur ^ 1);
      asm volatile("s_waitcnt vmcnt(8)" ::: "memory");
    } else {
      asm volatile("s_waitcnt vmcnt(0)" ::: "memory");
    }
    __builtin_amdgcn_s_barrier();
    __builtin_amdgcn_sched_barrier(0);

    short8 bf[4][2];
#pragma unroll
    for (int n = 0; n < 4; ++n) {
      bf[n][0] = *reinterpret_cast<const short8*>(&Bs[cur][brow + n * 1024 + s0]);
      bf[n][1] = *reinterpret_cast<const short8*>(&Bs[cur][brow + n * 1024 + s1]);
    }
    short8 af[4][2];
#pragma unroll
    for (int m = 0; m < 4; ++m) {
      af[m][0] = *reinterpret_cast<const short8*>(&As[cur][arow + m * 1024 + s0]);
      af[m][1] = *reinterpret_cast<const short8*>(&As[cur][arow + m * 1024 + s1]);
    }
    __builtin_amdgcn_s_setprio(1);
#pragma unroll
    for (int m = 0; m < 4; ++m)
#pragma unroll
      for (int n = 0; n < 4; ++n) {
        acc[m][n] = __builtin_amdgcn_mfma_f32_16x16x32_bf16(af[m][0], bf[n][0], acc[m][n], 0, 0, 0);
        acc[m][n] = __builtin_amdgcn_mfma_f32_16x16x32_bf16(af[m][1], bf[n][1], acc[m][n], 0, 0, 0);
      }
    __builtin_amdgcn_s_setprio(0);
    __builtin_amdgcn_s_barrier();
  }
#undef STAGE

  // ===================== epilogues =====================
  if constexpr (MODE == 1) {
    if (m0 < 512) {
      // P rows (g,ph) -> fp8: stage bytes [128][144], stream uint4
      unsigned char* SMe8 = (unsigned char*)SMu;
#pragma unroll
      for (int m = 0; m < 4; ++m)
#pragma unroll
        for (int n = 0; n < 4; ++n) {
          int col = wn * 64 + n * 16 + fr;
#pragma unroll
          for (int r = 0; r < 4; ++r) {
            int row = wm * 64 + m * 16 + fk * 4 + r;
            SMe8[row * 144 + col] = f2e4m3(acc[m][n][r] + bias[m0 + row]);
          }
        }
      __builtin_amdgcn_s_barrier();
      unsigned char* P8 = (unsigned char*)Cbase;
#pragma unroll
      for (int it = 0; it < 4; ++it) {
        int idx = it * 256 + tid;
        int row = idx >> 3, ch = idx & 7;
        int gcol = n0 + ch * 16;
        if (gcol < NSP)
          *reinterpret_cast<uint4*>(
              &P8[(size_t)b * 1605632 + (size_t)(m0 + row) * NSP + gcol]) =
              *reinterpret_cast<const uint4*>(&SMe8[row * 144 + ch * 16]);
      }
    } else {
      // th rows -> thT transposed bf16: SMe[n_local][j_local]
      ushort_t* SMe = SMu;            // [128][132]
      const int j0 = m0 - 512;
#pragma unroll
      for (int m = 0; m < 4; ++m)
#pragma unroll
        for (int n = 0; n < 4; ++n) {
          int nl = wn * 64 + n * 16 + fr;
#pragma unroll
          for (int r = 0; r < 4; ++r) {
            int jl = wm * 64 + m * 16 + fk * 4 + r;
            SMe[nl * 132 + jl] = f2b(acc[m][n][r] + bias[512 + j0 + jl]);
          }
        }
      __builtin_amdgcn_s_barrier();
      ushort_t* thT = (ushort_t*)C2;
#pragma unroll
      for (int it = 0; it < 8; ++it) {
        int idx = it * 256 + tid;
        int row = idx >> 4, ch = idx & 15;
        int gn = n0 + row;
        if (gn < NSP)
          *reinterpret_cast<us8*>(
              &thT[(size_t)b * 819200 + (size_t)gn * 256 + j0 + ch * 8]) =
              *reinterpret_cast<const us8*>(&SMe[row * 132 + ch * 8]);
      }
    }
  } else if constexpr (MODE == 6) {
    ushort_t* U = (ushort_t*)Cbase;
#pragma unroll
    for (int m = 0; m < 4; ++m)
#pragma unroll
      for (int n = 0; n < 4; ++n) {
        int gcol = n0 + wn * 64 + n * 16 + fr;
#pragma unroll
        for (int r = 0; r < 4; ++r) {
          int grow = m0 + wm * 64 + m * 16 + fk * 4 + r;
          U[(size_t)b * 131072 + grow * 256 + gcol] = f2b(acc[m][n][r]);
        }
      }
  } else {
    // -------- MODE 4: LDS-roundtrip f32 epilogue, float4-coalesced --------
    float* out = (float*)Cbase;
    float* SMf = (float*)SMu;         // 64 rows x 132 floats
#pragma unroll
    for (int p = 0; p < 2; ++p) {
      if (wm == p) {
#pragma unroll
        for (int m = 0; m < 4; ++m)
#pragma unroll
          for (int n = 0; n < 4; ++n) {
            int col = wn * 64 + n * 16 + fr;
#pragma unroll
            for (int r = 0; r < 4; ++r)
              SMf[(m * 16 + fk * 4 + r) * 132 + col] = acc[m][n][r];
          }
      }
      __builtin_amdgcn_s_barrier();
#pragma unroll
      for (int it = 0; it < 8; ++it) {
        int idx = it * 256 + tid;
        int row = idx >> 5, ch = idx & 31;
        int gcol = n0 + ch * 4;
        if (gcol < NSP) {
          int grow = m0 + p * 64 + row;
          size_t o = ((size_t)b * 512 + grow) * NSP + gcol;
          f32x4 v = *reinterpret_cast<const f32x4*>(&SMf[row * 132 + ch * 4]);
          f32x4 xr = *reinterpret_cast<const f32x4*>(&xres[o]);
          float bi = bias[grow];
          f32x4 ov = {v[0] + bi + xr[0], v[1] + bi + xr[1],
                      v[2] + bi + xr[2], v[3] + bi + xr[3]};
          *reinterpret_cast<f32x4*>(&out[o]) = ov;
        }
      }
      __builtin_amdgcn_s_barrier();
    }
  }
}

// ============ G2 fp8: Mf2 partials = ph8 .NT g8 (K=3136 split 7x448) ============
__global__ __launch_bounds__(256, 2) void g2_fp8(
    const unsigned char* __restrict__ P8, float* __restrict__ Mf)
{
  const int nwg = gridDim.x * gridDim.y * gridDim.z;   // 448, %8==0
  int flat = blockIdx.x + gridDim.x * (blockIdx.y + gridDim.y * blockIdx.z);
  const int q = nwg >> 3;
  int swz = (flat & 7) * q + (flat >> 3);
  const int bx = swz % gridDim.x; int tmp = swz / gridDim.x;
  const int by = tmp % gridDim.y;
  const int bz = tmp / gridDim.y;
  const int b = bz & 15, kc = bz >> 4;

  const unsigned char* A = P8 + (size_t)b * 1605632 + 802816;  // ph rows
  const unsigned char* B = P8 + (size_t)b * 1605632;           // g rows
  const int kbeg = kc * 448;

  const int m0 = bx * 128, n0 = by * 128;
  const int tid = threadIdx.x;
  const int lane = tid & 63;
  const int wid = tid >> 6;
  const int wm = wid >> 1, wn = wid & 1;
  const int fr = lane & 15;
  const int fk = lane >> 4;

  __shared__ __align__(16) unsigned char As8[2][8192];
  __shared__ __align__(16) unsigned char Bs8[2][8192];

  f32x4 acc[4][4];
#pragma unroll
  for (int i = 0; i < 4; ++i)
#pragma unroll
    for (int j = 0; j < 4; ++j) acc[i][j] = f32x4{0.f, 0.f, 0.f, 0.f};

  // staging: row = pass*64 + (tid>>2), pair = tid&3, swizzled source pair
  const int swzs = ((tid >> 2) & 3) ^ ((tid >> 4) & 3);
  const unsigned char* pa = A + (size_t)((tid >> 2)) * NSP + kbeg + ((tid & 3) ^ swzs) * 16;
  const unsigned char* pb = B + (size_t)((tid >> 2)) * NSP + kbeg + ((tid & 3) ^ swzs) * 16;
  pa += (size_t)m0 * NSP;
  pb += (size_t)n0 * NSP;

#define STAGE8(bufi) do { \
    __builtin_amdgcn_global_load_lds(AS1(pa), AS3(&As8[bufi][tid * 16]), 16, 0, 0); \
    __builtin_amdgcn_global_load_lds(AS1(pa + (size_t)64 * NSP), AS3(&As8[bufi][4096 + tid * 16]), 16, 0, 0); \
    __builtin_amdgcn_global_load_lds(AS1(pb), AS3(&Bs8[bufi][tid * 16]), 16, 0, 0); \
    __builtin_amdgcn_global_load_lds(AS1(pb + (size_t)64 * NSP), AS3(&Bs8[bufi][4096 + tid * 16]), 16, 0, 0); \
    pa += 64; pb += 64; \
  } while (0)

  // read: frag (s, fk) at pair = (2s + (fk>>1)) ^ swzr, half = fk&1
  const int swzr = (fr & 3) ^ ((fr >> 2) & 3);
  const int fo0 = (((fk >> 1) + 0) ^ swzr) * 16 + (fk & 1) * 8;
  const int fo1 = (((fk >> 1) + 2) ^ swzr) * 16 + (fk & 1) * 8;
  const int arow = (wm * 64 + fr) * 64;
  const int brow = (wn * 64 + fr) * 64;

  asm volatile("s_waitcnt vmcnt(0)" ::: "memory");
  STAGE8(0);

  for (int t = 0; t < 7; ++t) {
    const int cur = t & 1;
    if (t + 1 < 7) {
      STAGE8(cur ^ 1);
      asm volatile("s_waitcnt vmcnt(4)" ::: "memory");
    } else {
      asm volatile("s_waitcnt vmcnt(0)" ::: "memory");
    }
    __builtin_amdgcn_s_barrier();
    __builtin_amdgcn_sched_barrier(0);

    long a8[4][2], b8[4][2];
#pragma unroll
    for (int n = 0; n < 4; ++n) {
      b8[n][0] = *reinterpret_cast<const long*>(&Bs8[cur][brow + n * 1024 + fo0]);
      b8[n][1] = *reinterpret_cast<const long*>(&Bs8[cur][brow + n * 1024 + fo1]);
    }
#pragma unroll
    for (int m = 0; m < 4; ++m) {
      a8[m][0] = *reinterpret_cast<const long*>(&As8[cur][arow + m * 1024 + fo0]);
      a8[m][1] = *reinterpret_cast<const long*>(&As8[cur][arow + m * 1024 + fo1]);
    }
    __builtin_amdgcn_s_setprio(1);
#pragma unroll
    for (int m = 0; m < 4; ++m)
#pragma unroll
      for (int n = 0; n < 4; ++n) {
        acc[m][n] = __builtin_amdgcn_mfma_f32_16x16x32_fp8_fp8(a8[m][0], b8[n][0], acc[m][n], 0, 0, 0);
        acc[m][n] = __builtin_amdgcn_mfma_f32_16x16x32_fp8_fp8(a8[m][1], b8[n][1], acc[m][n], 0, 0, 0);
      }
    __builtin_amdgcn_s_setprio(0);
    __builtin_amdgcn_s_barrier();
  }
#undef STAGE8

#pragma unroll
  for (int m = 0; m < 4; ++m)
#pragma unroll
    for (int n = 0; n < 4; ++n) {
      int gcol = n0 + wn * 64 + n * 16 + fr;
#pragma unroll
      for (int r = 0; r < 4; ++r) {
        int grow = m0 + wm * 64 + m * 16 + fk * 4 + r;
        Mf[((size_t)kc * 16 + b) * 65536 + grow * 256 + gcol] = acc[m][n][r];
      }
    }
}

// x [b][512][3136] f32 -> xb [b][3136][512] bf16
__global__ __launch_bounds__(256) void transp_x(const float* __restrict__ x,
                                                ushort_t* __restrict__ xb)
{
  const int nt = blockIdx.x, ct = blockIdx.y, b = blockIdx.z;
  const int t = threadIdx.x;
  const int n0 = nt * 64, c0 = ct * 64;
  __shared__ float Ls[64 * 65];

  const float* xs = x + (size_t)b * 512 * NSP;
#pragma unroll
  for (int p = 0; p < 4; ++p) {
    int cl = p * 16 + (t >> 4);
    int nl = (t & 15) * 4;
    f32x4 v = *reinterpret_cast<const f32x4*>(&xs[(size_t)(c0 + cl) * NSP + n0 + nl]);
    Ls[cl * 65 + nl + 0] = v[0];
    Ls[cl * 65 + nl + 1] = v[1];
    Ls[cl * 65 + nl + 2] = v[2];
    Ls[cl * 65 + nl + 3] = v[3];
  }
  __syncthreads();
#pragma unroll
  for (int it = 0; it < 2; ++it) {
    int idx = it * 256 + t; int nl = idx >> 3, cc = idx & 7;
    us8 o;
#pragma unroll
    for (int j = 0; j < 8; ++j) o[j] = f2b(Ls[(cc * 8 + j) * 65 + nl]);
    *reinterpret_cast<us8*>(&xb[((size_t)b * NSP + n0 + nl) * 512 + c0 + cc * 8]) = o;
  }
}

__global__ __launch_bounds__(256) void prep_weights(
    const float* __restrict__ g_w, const float* __restrict__ ph_w,
    const float* __restrict__ th_w, const float* __restrict__ W_w,
    const float* __restrict__ g_b, const float* __restrict__ ph_b,
    const float* __restrict__ th_b,
    ushort_t* __restrict__ W3, ushort_t* __restrict__ Wwb,
    float* __restrict__ bias3)
{
  int i = blockIdx.x * 256 + threadIdx.x;
  if (i < 393216) {
    int row = i >> 9, col = i & 511;
    float v = (row < 256) ? g_w[row * 512 + col]
            : (row < 512) ? ph_w[(row - 256) * 512 + col]
                          : th_w[(row - 512) * 512 + col];
    W3[i] = f2b(v);
  } else if (i < 524288) {
    Wwb[i - 393216] = f2b(W_w[i - 393216]);
  } else if (i < 525056) {
    int r = i - 524288;
    bias3[r] = (r < 256) ? g_b[r] : (r < 512) ? ph_b[r - 256] : th_b[r - 512];
  }
}

__global__ __launch_bounds__(256) void cvt_M(const float* __restrict__ Mf,
                                             ushort_t* __restrict__ MT)
{
  int i = blockIdx.x * 256 + threadIdx.x;   // 16*256*256
  const int SL = 1048576;
  float s = 0.f;
#pragma unroll
  for (int k = 0; k < 7; ++k) s += Mf[(size_t)k * SL + i];
  MT[i] = f2b(s * (1.0f / 3136.0f));
}

extern "C" void kernel_launch(void* const* d_in, const int* in_sizes, int n_in,
                              void* d_out, int out_size, void* d_ws, size_t ws_size,
                              hipStream_t stream) {
  const float* x    = (const float*)d_in[0];
  const float* g_w  = (const float*)d_in[1];
  const float* g_b  = (const float*)d_in[2];
  const float* th_w = (const float*)d_in[3];
  const float* th_b = (const float*)d_in[4];
  const float* ph_w = (const float*)d_in[5];
  const float* ph_b = (const float*)d_in[6];
  const float* W_w  = (const float*)d_in[7];
  const float* W_b  = (const float*)d_in[8];

  char* ws = (char*)d_ws;
  ushort_t*      xb   = (ushort_t*)(ws + 0);           // 51,380,224 (dead after G1)
  float*         Mf2  = (float*)(ws + 0);              // 29,360,128 (alias xb)
  ushort_t*      MT2  = (ushort_t*)(ws + 29360128);    // 2,097,152 (alias xb)
  ushort_t*      U    = (ushort_t*)(ws + 31457280);    // 4,194,304 (alias xb)
  unsigned char* P8   = (unsigned char*)(ws + 51380224); // 25,690,112 (dead after G2)
  ushort_t*      thT  = (ushort_t*)(ws + 77070336);    // 26,214,400 (+64KB slop)
  ushort_t*      W3   = (ushort_t*)(ws + 103415808);   // 786,432
  ushort_t*      Wwb  = (ushort_t*)(ws + 104202240);   // 262,144
  float*         bias3 = (float*)(ws + 104464384);     // 3,072

  prep_weights<<<2052, 256, 0, stream>>>(g_w, ph_w, th_w, W_w, g_b, ph_b, th_b,
                                         W3, Wwb, bias3);
  transp_x<<<dim3(49, 8, 16), 256, 0, stream>>>(x, xb);

  // G1: P8(g,ph fp8) + thT(bf16) = W3 .NT xb (+bias3)   M=768, K=512
  gemm64<1><<<dim3(6, 26, 16), 256, 0, stream>>>(W3, xb, P8, thT, bias3, nullptr);
  // G2: Mf2 partials = ph8 .NT g8   split-K 7x448 (fp8 MFMA)
  g2_fp8<<<dim3(2, 2, 112), 256, 0, stream>>>(P8, Mf2);
  cvt_M<<<4096, 256, 0, stream>>>(Mf2, MT2);
  // GU: U = Wwb .NT MT2            M=512, N=256, K=256
  gemm64<6><<<dim3(4, 2, 16), 256, 0, stream>>>(Wwb, MT2, U, nullptr, nullptr, nullptr);
  // G4: out = U .NT thT + x + W_b  M=512, N=3328-tiled, K=256
  gemm64<4><<<dim3(4, 26, 16), 256, 0, stream>>>(U, thT, d_out, nullptr, W_b, x);
}

// Round 13
// 162.176 us; speedup vs baseline: 1.1443x; 1.1443x over previous
//
#include <hip/hip_runtime.h>
#include <stdint.h>

// ---------------------------------------------------------------------------
// NonLocalBlock2D  B=16, C=512, I=256, N=3136.  (R11 final: all GEMMs on the
// 128^2 gemm64 chassis: 64KiB LDS -> 2 blocks/CU so epilogue/prologue of one
// block overlaps the K-loop of the co-resident one.)
//   xb  [b][3136][512] = x^T bf16
//   G1 (MODE1): m-tiles 0-3 -> P[b][512][3136] (g,ph) ; m-tiles 4-5 -> thT
//               (transposed store, [b][3200 alloc][256], rows>=3136 unwritten)
//   G2 (MODE2): Mf2 partials = ph .NT g, split-K 7x448
//   cvt: MT2 = (1/N) sum partials
//   GU (MODE6): U = Ww .NT MT2
//   G4 (MODE4): out = U .NT thT + x + W_b  (f32 LDS-roundtrip epilogue)
// ---------------------------------------------------------------------------

typedef unsigned short ushort_t;
typedef __attribute__((ext_vector_type(8))) short short8;
typedef __attribute__((ext_vector_type(4))) float f32x4;
typedef __attribute__((ext_vector_type(8))) unsigned short us8;

#define NSP  3136

#define AS1(p) ((const __attribute__((address_space(1))) void*)(p))
#define AS3(p) ((__attribute__((address_space(3))) void*)(p))

__device__ inline ushort_t f2b(float f) {
  union { float f; uint32_t u; } c; c.f = f;
  uint32_t u = c.u;
  uint32_t r = (u + 0x7fffu + ((u >> 16) & 1u)) >> 16;
  return (ushort_t)r;
}

// MODE 1: G1 : A=W3[768][512], B=xb_b, K=512.  C-> P (m0<512) / thT (m0>=512)
// MODE 2: G2 : Mf2 = ph .NT g  (K=3136 split 7x448) f32 partials
// MODE 6: GU : U = Ww .NT MT2  (K=256) bf16
// MODE 4: G4 : out = U .NT thT + x + W_b (K=256) f32
template<int MODE>
__global__ __launch_bounds__(256, 2) void gemm64(
    const ushort_t* __restrict__ Abase,
    const ushort_t* __restrict__ Bbase,
    void* __restrict__ Cbase, void* __restrict__ C2,
    const float* __restrict__ bias,
    const float* __restrict__ xres)
{
  constexpr int TB = 256;
  constexpr int CH = TB / 8;           // 32 rows per stage chunk

  const int nwg = gridDim.x * gridDim.y * gridDim.z;
  int flat = blockIdx.x + gridDim.x * (blockIdx.y + gridDim.y * blockIdx.z);
  const int q = nwg >> 3;
  int swz = (flat & 7) * q + (flat >> 3);
  const int bx = swz % gridDim.x; int tmp = swz / gridDim.x;
  const int by = tmp % gridDim.y;
  const int bz = tmp / gridDim.y;

  int b = bz, kc = 0, kbeg = 0, kend, lda, ldb;
  const ushort_t *A, *B;
  if constexpr (MODE == 1) {
    A = Abase;                                   // W3
    B = Bbase + (size_t)b * 1605632;             // xb_b (3136x512)
    lda = 512; ldb = 512; kend = 512;
  } else if constexpr (MODE == 2) {
    b = bz & 15; kc = bz >> 4;
    A = Abase + (size_t)b * 1605632 + 802816;    // ph rows of P_b
    B = Abase + (size_t)b * 1605632;             // g rows
    lda = NSP; ldb = NSP; kbeg = kc * 448; kend = kbeg + 448;
  } else if constexpr (MODE == 6) {
    A = Abase; lda = 256;                        // Wwb [512][256]
    B = Bbase + (size_t)b * 65536; ldb = 256;    // MT2_b
    kend = 256;
  } else {
    A = Abase + (size_t)b * 131072; lda = 256;   // U_b [512][256]
    B = Bbase + (size_t)b * 819200; ldb = 256;   // thT_b ([3200][256] alloc)
    kend = 256;
  }

  const int m0 = bx * 128;
  const int n0 = by * 128;
  const int tid = threadIdx.x;
  const int lane = tid & 63;
  const int wid = tid >> 6;
  const int wm = wid >> 1, wn = wid & 1;
  const int fr = lane & 15;
  const int fk = lane >> 4;

  __shared__ __align__(16) ushort_t SMu[32768];   // 64 KiB: As | Bs, reused by epilogues
  ushort_t (*As)[8192] = (ushort_t(*)[8192])(SMu);
  ushort_t (*Bs)[8192] = (ushort_t(*)[8192])(SMu + 16384);

  f32x4 acc[4][4];
#pragma unroll
  for (int i = 0; i < 4; ++i)
#pragma unroll
    for (int j = 0; j < 4; ++j) acc[i][j] = f32x4{0.f, 0.f, 0.f, 0.f};

  const int srow = tid >> 3;
  const int lsl = (tid & 7) ^ (srow & 7);
  const ushort_t* pa = A + (size_t)(m0 + srow) * lda + kbeg + lsl * 8;
  const ushort_t* pb = B + (size_t)(n0 + srow) * ldb + kbeg + lsl * 8;

#define STAGE(bufi) do {                                                              \
    __builtin_amdgcn_global_load_lds(AS1(pa),                    AS3(&As[bufi][tid * 8]), 16, 0, 0); \
    __builtin_amdgcn_global_load_lds(AS1(pa + (size_t)CH * lda), AS3(&As[bufi][TB * 8 + tid * 8]), 16, 0, 0); \
    __builtin_amdgcn_global_load_lds(AS1(pa + (size_t)2 * CH * lda), AS3(&As[bufi][2 * TB * 8 + tid * 8]), 16, 0, 0); \
    __builtin_amdgcn_global_load_lds(AS1(pa + (size_t)3 * CH * lda), AS3(&As[bufi][3 * TB * 8 + tid * 8]), 16, 0, 0); \
    __builtin_amdgcn_global_load_lds(AS1(pb),                    AS3(&Bs[bufi][tid * 8]), 16, 0, 0); \
    __builtin_amdgcn_global_load_lds(AS1(pb + (size_t)CH * ldb), AS3(&Bs[bufi][TB * 8 + tid * 8]), 16, 0, 0); \
    __builtin_amdgcn_global_load_lds(AS1(pb + (size_t)2 * CH * ldb), AS3(&Bs[bufi][2 * TB * 8 + tid * 8]), 16, 0, 0); \
    __builtin_amdgcn_global_load_lds(AS1(pb + (size_t)3 * CH * ldb), AS3(&Bs[bufi][3 * TB * 8 + tid * 8]), 16, 0, 0); \
    pa += 64; pb += 64;                                                               \
  } while (0)

  const int sw = fr & 7;
  const int s0 = ((0 | fk) ^ sw) * 8;
  const int s1 = ((4 | fk) ^ sw) * 8;
  const int arow = (wm * 64 + fr) * 64;
  const int brow = (wn * 64 + fr) * 64;

  asm volatile("s_waitcnt vmcnt(0)" ::: "memory");
  STAGE(0);

  const int nkt = (kend - kbeg) >> 6;
  for (int t = 0; t < nkt; ++t) {
    const int cur = t & 1;
    if (t + 1 < nkt) {
      STAGE(cur ^ 1);
      asm volatile("s_waitcnt vmcnt(8)" ::: "memory");
    } else {
      asm volatile("s_waitcnt vmcnt(0)" ::: "memory");
    }
    __builtin_amdgcn_s_barrier();
    __builtin_amdgcn_sched_barrier(0);

    short8 bf[4][2];
#pragma unroll
    for (int n = 0; n < 4; ++n) {
      bf[n][0] = *reinterpret_cast<const short8*>(&Bs[cur][brow + n * 1024 + s0]);
      bf[n][1] = *reinterpret_cast<const short8*>(&Bs[cur][brow + n * 1024 + s1]);
    }
    short8 af[4][2];
#pragma unroll
    for (int m = 0; m < 4; ++m) {
      af[m][0] = *reinterpret_cast<const short8*>(&As[cur][arow + m * 1024 + s0]);
      af[m][1] = *reinterpret_cast<const short8*>(&As[cur][arow + m * 1024 + s1]);
    }
    __builtin_amdgcn_s_setprio(1);
#pragma unroll
    for (int m = 0; m < 4; ++m)
#pragma unroll
      for (int n = 0; n < 4; ++n) {
        acc[m][n] = __builtin_amdgcn_mfma_f32_16x16x32_bf16(af[m][0], bf[n][0], acc[m][n], 0, 0, 0);
        acc[m][n] = __builtin_amdgcn_mfma_f32_16x16x32_bf16(af[m][1], bf[n][1], acc[m][n], 0, 0, 0);
      }
    __builtin_amdgcn_s_setprio(0);
    __builtin_amdgcn_s_barrier();
  }
#undef STAGE

  // ===================== epilogues =====================
  if constexpr (MODE == 1) {
    ushort_t* SMe = SMu;              // [128][132] ushort = 33,792 B
    if (m0 < 512) {
      // P rows (g,ph): single-pass stage, coalesced us8 out
#pragma unroll
      for (int m = 0; m < 4; ++m)
#pragma unroll
        for (int n = 0; n < 4; ++n) {
          int col = wn * 64 + n * 16 + fr;
#pragma unroll
          for (int r = 0; r < 4; ++r) {
            int row = wm * 64 + m * 16 + fk * 4 + r;
            SMe[row * 132 + col] = f2b(acc[m][n][r] + bias[m0 + row]);
          }
        }
      __builtin_amdgcn_s_barrier();
      ushort_t* P = (ushort_t*)Cbase;
#pragma unroll
      for (int it = 0; it < 8; ++it) {
        int idx = it * 256 + tid;
        int row = idx >> 4, ch = idx & 15;
        int gcol = n0 + ch * 8;
        if (gcol < NSP)
          *reinterpret_cast<us8*>(
              &P[(size_t)b * 512 * NSP + (size_t)(m0 + row) * NSP + gcol]) =
              *reinterpret_cast<const us8*>(&SMe[row * 132 + ch * 8]);
      }
    } else {
      // th rows -> thT transposed: SMe[n_local][j_local]
      const int j0 = m0 - 512;
#pragma unroll
      for (int m = 0; m < 4; ++m)
#pragma unroll
        for (int n = 0; n < 4; ++n) {
          int nl = wn * 64 + n * 16 + fr;
#pragma unroll
          for (int r = 0; r < 4; ++r) {
            int jl = wm * 64 + m * 16 + fk * 4 + r;
            SMe[nl * 132 + jl] = f2b(acc[m][n][r] + bias[512 + j0 + jl]);
          }
        }
      __builtin_amdgcn_s_barrier();
      ushort_t* thT = (ushort_t*)C2;
#pragma unroll
      for (int it = 0; it < 8; ++it) {
        int idx = it * 256 + tid;
        int row = idx >> 4, ch = idx & 15;
        int gn = n0 + row;
        if (gn < NSP)
          *reinterpret_cast<us8*>(
              &thT[(size_t)b * 819200 + (size_t)gn * 256 + j0 + ch * 8]) =
              *reinterpret_cast<const us8*>(&SMe[row * 132 + ch * 8]);
      }
    }
  } else if constexpr (MODE == 2) {
    float* Mf = (float*)Cbase;
#pragma unroll
    for (int m = 0; m < 4; ++m)
#pragma unroll
      for (int n = 0; n < 4; ++n) {
        int gcol = n0 + wn * 64 + n * 16 + fr;
#pragma unroll
        for (int r = 0; r < 4; ++r) {
          int grow = m0 + wm * 64 + m * 16 + fk * 4 + r;
          Mf[((size_t)kc * 16 + b) * 65536 + grow * 256 + gcol] = acc[m][n][r];
        }
      }
  } else if constexpr (MODE == 6) {
    ushort_t* U = (ushort_t*)Cbase;
#pragma unroll
    for (int m = 0; m < 4; ++m)
#pragma unroll
      for (int n = 0; n < 4; ++n) {
        int gcol = n0 + wn * 64 + n * 16 + fr;
#pragma unroll
        for (int r = 0; r < 4; ++r) {
          int grow = m0 + wm * 64 + m * 16 + fk * 4 + r;
          U[(size_t)b * 131072 + grow * 256 + gcol] = f2b(acc[m][n][r]);
        }
      }
  } else {
    // -------- MODE 4: LDS-roundtrip f32 epilogue, float4-coalesced --------
    float* out = (float*)Cbase;
    float* SMf = (float*)SMu;         // 64 rows x 132 floats
#pragma unroll
    for (int p = 0; p < 2; ++p) {
      if (wm == p) {
#pragma unroll
        for (int m = 0; m < 4; ++m)
#pragma unroll
          for (int n = 0; n < 4; ++n) {
            int col = wn * 64 + n * 16 + fr;
#pragma unroll
            for (int r = 0; r < 4; ++r)
              SMf[(m * 16 + fk * 4 + r) * 132 + col] = acc[m][n][r];
          }
      }
      __builtin_amdgcn_s_barrier();
#pragma unroll
      for (int it = 0; it < 8; ++it) {
        int idx = it * 256 + tid;
        int row = idx >> 5, ch = idx & 31;
        int gcol = n0 + ch * 4;
        if (gcol < NSP) {
          int grow = m0 + p * 64 + row;
          size_t o = ((size_t)b * 512 + grow) * NSP + gcol;
          f32x4 v = *reinterpret_cast<const f32x4*>(&SMf[row * 132 + ch * 4]);
          f32x4 xr = *reinterpret_cast<const f32x4*>(&xres[o]);
          float bi = bias[grow];
          f32x4 ov = {v[0] + bi + xr[0], v[1] + bi + xr[1],
                      v[2] + bi + xr[2], v[3] + bi + xr[3]};
          *reinterpret_cast<f32x4*>(&out[o]) = ov;
        }
      }
      __builtin_amdgcn_s_barrier();
    }
  }
}

// x [b][512][3136] f32 -> xb [b][3136][512] bf16
__global__ __launch_bounds__(256) void transp_x(const float* __restrict__ x,
                                                ushort_t* __restrict__ xb)
{
  const int nt = blockIdx.x, ct = blockIdx.y, b = blockIdx.z;
  const int t = threadIdx.x;
  const int n0 = nt * 64, c0 = ct * 64;
  __shared__ float Ls[64 * 65];

  const float* xs = x + (size_t)b * 512 * NSP;
#pragma unroll
  for (int p = 0; p < 4; ++p) {
    int cl = p * 16 + (t >> 4);
    int nl = (t & 15) * 4;
    f32x4 v = *reinterpret_cast<const f32x4*>(&xs[(size_t)(c0 + cl) * NSP + n0 + nl]);
    Ls[cl * 65 + nl + 0] = v[0];
    Ls[cl * 65 + nl + 1] = v[1];
    Ls[cl * 65 + nl + 2] = v[2];
    Ls[cl * 65 + nl + 3] = v[3];
  }
  __syncthreads();
#pragma unroll
  for (int it = 0; it < 2; ++it) {
    int idx = it * 256 + t; int nl = idx >> 3, cc = idx & 7;
    us8 o;
#pragma unroll
    for (int j = 0; j < 8; ++j) o[j] = f2b(Ls[(cc * 8 + j) * 65 + nl]);
    *reinterpret_cast<us8*>(&xb[((size_t)b * NSP + n0 + nl) * 512 + c0 + cc * 8]) = o;
  }
}

__global__ __launch_bounds__(256) void prep_weights(
    const float* __restrict__ g_w, const float* __restrict__ ph_w,
    const float* __restrict__ th_w, const float* __restrict__ W_w,
    const float* __restrict__ g_b, const float* __restrict__ ph_b,
    const float* __restrict__ th_b,
    ushort_t* __restrict__ W3, ushort_t* __restrict__ Wwb,
    float* __restrict__ bias3)
{
  int i = blockIdx.x * 256 + threadIdx.x;
  if (i < 393216) {
    int row = i >> 9, col = i & 511;
    float v = (row < 256) ? g_w[row * 512 + col]
            : (row < 512) ? ph_w[(row - 256) * 512 + col]
                          : th_w[(row - 512) * 512 + col];
    W3[i] = f2b(v);
  } else if (i < 524288) {
    Wwb[i - 393216] = f2b(W_w[i - 393216]);
  } else if (i < 525056) {
    int r = i - 524288;
    bias3[r] = (r < 256) ? g_b[r] : (r < 512) ? ph_b[r - 256] : th_b[r - 512];
  }
}

__global__ __launch_bounds__(256) void cvt_M(const float* __restrict__ Mf,
                                             ushort_t* __restrict__ MT)
{
  int i = blockIdx.x * 256 + threadIdx.x;   // 16*256*256
  const int SL = 1048576;
  float s = 0.f;
#pragma unroll
  for (int k = 0; k < 7; ++k) s += Mf[(size_t)k * SL + i];
  MT[i] = f2b(s * (1.0f / 3136.0f));
}

extern "C" void kernel_launch(void* const* d_in, const int* in_sizes, int n_in,
                              void* d_out, int out_size, void* d_ws, size_t ws_size,
                              hipStream_t stream) {
  const float* x    = (const float*)d_in[0];
  const float* g_w  = (const float*)d_in[1];
  const float* g_b  = (const float*)d_in[2];
  const float* th_w = (const float*)d_in[3];
  const float* th_b = (const float*)d_in[4];
  const float* ph_w = (const float*)d_in[5];
  const float* ph_b = (const float*)d_in[6];
  const float* W_w  = (const float*)d_in[7];
  const float* W_b  = (const float*)d_in[8];

  char* ws = (char*)d_ws;
  ushort_t* xb   = (ushort_t*)(ws + 0);            // 51,380,224 (dead after G1)
  float*    Mf2  = (float*)(ws + 0);               // 29,360,128 (alias xb)
  ushort_t* MT2  = (ushort_t*)(ws + 29360128);     // 2,097,152 (alias xb)
  ushort_t* U    = (ushort_t*)(ws + 31457280);     // 4,194,304 (alias xb)
  ushort_t* P    = (ushort_t*)(ws + 51380224);     // 51,380,224 (dead after G2)
  ushort_t* thT  = (ushort_t*)(ws + 102760448);    // 26,214,400
  ushort_t* W3   = (ushort_t*)(ws + 128974848);    // 786,432
  ushort_t* Wwb  = (ushort_t*)(ws + 129761280);    // 262,144
  float*    bias3 = (float*)(ws + 130023424);      // 3,072

  prep_weights<<<2052, 256, 0, stream>>>(g_w, ph_w, th_w, W_w, g_b, ph_b, th_b,
                                         W3, Wwb, bias3);
  transp_x<<<dim3(49, 8, 16), 256, 0, stream>>>(x, xb);

  // G1: P(g,ph) + thT = W3 .NT xb (+bias3)   M=768, N=3328-tiled, K=512
  gemm64<1><<<dim3(6, 26, 16), 256, 0, stream>>>(W3, xb, P, thT, bias3, nullptr);
  // G2: Mf2 partials = ph .NT g   split-K 7x448
  gemm64<2><<<dim3(2, 2, 112), 256, 0, stream>>>(P, nullptr, Mf2, nullptr, nullptr, nullptr);
  cvt_M<<<4096, 256, 0, stream>>>(Mf2, MT2);
  // GU: U = Wwb .NT MT2            M=512, N=256, K=256
  gemm64<6><<<dim3(4, 2, 16), 256, 0, stream>>>(Wwb, MT2, U, nullptr, nullptr, nullptr);
  // G4: out = U .NT thT + x + W_b  M=512, N=3328-tiled, K=256
  gemm64<4><<<dim3(4, 26, 16), 256, 0, stream>>>(U, thT, d_out, nullptr, W_b, x);
}